// Round 14
// baseline (56.557 us; speedup 1.0000x reference)
//
#include <hip/hip_runtime.h>

#define FD 128  // feature dim

typedef __attribute__((ext_vector_type(8))) short short8;   // 8 bf16
typedef __attribute__((ext_vector_type(4))) float f32x4;    // MFMA acc

__device__ __forceinline__ unsigned short f2bf(float f) {
    unsigned u = __float_as_uint(f);
    u += 0x7fff + ((u >> 16) & 1);   // round-to-nearest-even
    return (unsigned short)(u >> 16);
}
__device__ __forceinline__ float bf2f(unsigned short h) {
    return __uint_as_float(((unsigned)h) << 16);
}
// exact signed-int8 dot of 4 packed bytes
__device__ __forceinline__ int bdot4(unsigned x, unsigned y, int acc) {
#if __has_builtin(__builtin_amdgcn_sdot4)
    return __builtin_amdgcn_sdot4(x, y, acc, false);
#else
    acc += (((int)(x << 24)) >> 24) * (((int)(y << 24)) >> 24);
    acc += (((int)(x << 16)) >> 24) * (((int)(y << 16)) >> 24);
    acc += (((int)(x <<  8)) >> 24) * (((int)(y <<  8)) >> 24);
    acc += (((int)x) >> 24)         * (((int)y) >> 24);
    return acc;
#endif
}
__device__ __forceinline__ unsigned pack4f(float a, float b, float c, float d, float inv) {
    const int q0 = (int)rintf(a * inv), q1 = (int)rintf(b * inv);
    const int q2 = (int)rintf(c * inv), q3 = (int)rintf(d * inv);
    return (unsigned)(q0 & 255) | ((unsigned)(q1 & 255) << 8) |
           ((unsigned)(q2 & 255) << 16) | ((unsigned)(q3 & 255) << 24);
}

// ---------------------------------------------------------------------------
// Kernel 0: Wt[n][k] = bf16(W[k][n])  (128x128), short8 outputs.
// ---------------------------------------------------------------------------
__global__ void wt_kernel(const float* __restrict__ W, unsigned short* __restrict__ Wt) {
    const int tid = blockIdx.x * 256 + (int)threadIdx.x;   // 0..2047
    const int n  = tid & 127;
    const int k0 = (tid >> 7) * 8;
    short8 w;
    #pragma unroll
    for (int j = 0; j < 8; ++j) w[j] = (short)f2bf(W[(k0 + j) * FD + n]);
    *(short8*)(Wt + (size_t)n * FD + k0) = w;
}

// ---------------------------------------------------------------------------
// Kernel 1 (v9): PERSISTENT fused u8/z8 int8-rowquant producer.
// = v8 (swapped-operand MFMA D[i][j] = u[j][i], pure-register epilogue,
// verified identical output) + persistence & pipelining:
//  - ~768 blocks grid-stride over 64-row tiles; Wt staged in LDS ONCE per
//    block (amortized), no barrier inside the loop.
//  - Next tile's 8 z float4 loads are issued immediately after the current
//    tile's zf registers are consumed into bf16 fragments, so tile N+1's
//    L3/HBM latency drains under tile N's 32 MFMAs + quantize + stores.
// Round-13 lesson: u-phase is latency/ramp-bound (z is L3-resident; steady
// FETCH ~26 MB), not instruction-bound — attack the per-tile latency chain.
// ---------------------------------------------------------------------------
__global__ __launch_bounds__(256)
void u_mfma9(const float* __restrict__ z, const unsigned short* __restrict__ Wt,
             unsigned char* __restrict__ u8, float* __restrict__ uscale,
             unsigned char* __restrict__ z8, float* __restrict__ zscale,
             int nrows, int ntiles) {
    __shared__ unsigned short Wl[FD * FD];  // 32 KB
    char* ldsb = (char*)Wl;
    const int tid  = (int)threadIdx.x;
    const int lane = tid & 63;
    const int wave = tid >> 6;
    const int l16  = lane & 15;
    const int kq   = lane >> 4;
    const long NB  = gridDim.x;

    // prologue: issue first tile's z loads BEFORE staging (hide under it)
    long tile = blockIdx.x;
    float4 zf[4][2];
    if (tile < ntiles) {
        const long r0  = tile * 64 + wave * 16 + l16;
        const long rc0 = (r0 < nrows) ? r0 : (long)(nrows - 1);
        #pragma unroll
        for (int ks = 0; ks < 4; ++ks) {
            const float4* zp = (const float4*)(z + rc0 * FD + kq * 32 + ks * 8);
            zf[ks][0] = zp[0];
            zf[ks][1] = zp[1];
        }
    }

    // stage Wt -> LDS once, swizzled: byte = n*256 + (o ^ ((n&7)<<4))
    #pragma unroll
    for (int i = 0; i < 8; ++i) {
        const int c = i * 256 + tid;
        const int n = c >> 4;
        const int o = (c & 15) * 16;
        short8 v = *(const short8*)(Wt + (size_t)n * FD + (c & 15) * 8);
        *(short8*)(ldsb + n * 256 + (o ^ ((n & 7) << 4))) = v;
    }
    __syncthreads();

    for (; tile < ntiles; tile += NB) {
        const long r  = tile * 64 + wave * 16 + l16;
        const bool rok = (r < nrows);

        // consume zf -> bf16 fragments + zmax (frees zf for the prefetch)
        short8 avk[4];
        float zmax = 1e-30f;
        #pragma unroll
        for (int ks = 0; ks < 4; ++ks) {
            const float4 f0 = zf[ks][0];
            const float4 f1 = zf[ks][1];
            short8 av;
            av[0] = (short)f2bf(f0.x); av[1] = (short)f2bf(f0.y);
            av[2] = (short)f2bf(f0.z); av[3] = (short)f2bf(f0.w);
            av[4] = (short)f2bf(f1.x); av[5] = (short)f2bf(f1.y);
            av[6] = (short)f2bf(f1.z); av[7] = (short)f2bf(f1.w);
            avk[ks] = av;
            #pragma unroll
            for (int j = 0; j < 8; ++j)
                zmax = fmaxf(zmax, fabsf(bf2f((unsigned short)av[j])));
        }

        // prefetch next tile's z (latency hides under MFMA + epilogue)
        const long tn = tile + NB;
        if (tn < ntiles) {
            const long rn  = tn * 64 + wave * 16 + l16;
            const long rcn = (rn < nrows) ? rn : (long)(nrows - 1);
            #pragma unroll
            for (int ks = 0; ks < 4; ++ks) {
                const float4* zp = (const float4*)(z + rcn * FD + kq * 32 + ks * 8);
                zf[ks][0] = zp[0];
                zf[ks][1] = zp[1];
            }
        }

        // MFMA: D = A(Wt) * B(z) => lane holds u[row r][32 consecutive cols]
        f32x4 acc[8];
        #pragma unroll
        for (int nt = 0; nt < 8; ++nt)
            acc[nt] = (f32x4){0.f, 0.f, 0.f, 0.f};
        #pragma unroll
        for (int ks = 0; ks < 4; ++ks) {
            #pragma unroll
            for (int nt = 0; nt < 8; ++nt) {
                const int row = nt * 16 + l16;
                const short8 a = *(const short8*)(
                    ldsb + row * 256 + ((kq * 64 + ks * 16) ^ ((row & 7) << 4)));
                acc[nt] = __builtin_amdgcn_mfma_f32_16x16x32_bf16(a, avk[ks], acc[nt], 0, 0, 0);
            }
        }

        // z8 store (row r, lane's 32 contiguous cols)
        zmax = fmaxf(zmax, __shfl_xor(zmax, 16, 64));
        zmax = fmaxf(zmax, __shfl_xor(zmax, 32, 64));
        {
            const float inv = 127.0f / zmax;
            uint4 p0, p1;
            p0.x = pack4f(bf2f((unsigned short)avk[0][0]), bf2f((unsigned short)avk[0][1]),
                          bf2f((unsigned short)avk[0][2]), bf2f((unsigned short)avk[0][3]), inv);
            p0.y = pack4f(bf2f((unsigned short)avk[0][4]), bf2f((unsigned short)avk[0][5]),
                          bf2f((unsigned short)avk[0][6]), bf2f((unsigned short)avk[0][7]), inv);
            p0.z = pack4f(bf2f((unsigned short)avk[1][0]), bf2f((unsigned short)avk[1][1]),
                          bf2f((unsigned short)avk[1][2]), bf2f((unsigned short)avk[1][3]), inv);
            p0.w = pack4f(bf2f((unsigned short)avk[1][4]), bf2f((unsigned short)avk[1][5]),
                          bf2f((unsigned short)avk[1][6]), bf2f((unsigned short)avk[1][7]), inv);
            p1.x = pack4f(bf2f((unsigned short)avk[2][0]), bf2f((unsigned short)avk[2][1]),
                          bf2f((unsigned short)avk[2][2]), bf2f((unsigned short)avk[2][3]), inv);
            p1.y = pack4f(bf2f((unsigned short)avk[2][4]), bf2f((unsigned short)avk[2][5]),
                          bf2f((unsigned short)avk[2][6]), bf2f((unsigned short)avk[2][7]), inv);
            p1.z = pack4f(bf2f((unsigned short)avk[3][0]), bf2f((unsigned short)avk[3][1]),
                          bf2f((unsigned short)avk[3][2]), bf2f((unsigned short)avk[3][3]), inv);
            p1.w = pack4f(bf2f((unsigned short)avk[3][4]), bf2f((unsigned short)avk[3][5]),
                          bf2f((unsigned short)avk[3][6]), bf2f((unsigned short)avk[3][7]), inv);
            if (rok) {
                *(uint4*)(z8 + r * FD + kq * 32)      = p0;
                *(uint4*)(z8 + r * FD + kq * 32 + 16) = p1;
                if (kq == 0) zscale[r] = zmax * (1.0f / 127.0f);
            }
        }

        // u epilogue, pure-register (v8-verified layout)
        float umax = 1e-30f;
        #pragma unroll
        for (int nt = 0; nt < 8; ++nt) {
            const f32x4 v = acc[nt];
            umax = fmaxf(umax, fmaxf(fmaxf(fabsf(v[0]), fabsf(v[1])),
                                     fmaxf(fabsf(v[2]), fabsf(v[3]))));
        }
        umax = fmaxf(umax, __shfl_xor(umax, 16, 64));
        umax = fmaxf(umax, __shfl_xor(umax, 32, 64));
        umax = fmaxf(umax, 1e-30f);
        const float uinv = 127.0f / umax;
        if (rok) {
            #pragma unroll
            for (int nt = 0; nt < 8; ++nt) {
                const f32x4 v = acc[nt];
                *(unsigned*)(u8 + r * FD + nt * 16 + kq * 4) =
                    pack4f(v[0], v[1], v[2], v[3], uinv);
            }
            if (kq == 0) uscale[r] = umax * (1.0f / 127.0f);
        }
    }
}

// ---------------------------------------------------------------------------
// Kernel 2 (v2): 3-stage pipelined int8 edge kernel (unchanged, ~26 us —
// within ~8% of the 164-MB gather floor at ~7 TB/s L3 BW).
// ---------------------------------------------------------------------------
__global__ __launch_bounds__(256)
void edge8p2(const unsigned char* __restrict__ u8, const unsigned char* __restrict__ z8,
             const float* __restrict__ uscale, const float* __restrict__ zscale,
             const int* __restrict__ src, const int* __restrict__ dst,
             const float* __restrict__ bias, float* __restrict__ out, int E) {
    const int tid  = (int)threadIdx.x;
    const int lane = tid & 63;
    const int sub  = lane >> 3;    // edge slot within wave (0..7)
    const int l8   = lane & 7;     // 16-B slice within the 128-B row
    const long wv  = (long)blockIdx.x * 4 + (tid >> 6);
    const long S   = (long)gridDim.x * 4 * 8;
    const float bv = bias[0];
    const long Em1 = (long)E - 1;

    long e = wv * 8 + sub;
    long ec  = (e     < E) ? e     : Em1;
    long ecn = (e + S < E) ? e + S : Em1;
    int s0 = src[ec],  t0 = dst[ec];
    int s1 = src[ecn], t1 = dst[ecn];
    uint4 xu0 = *((const uint4*)(u8 + (size_t)s0 * FD) + l8);
    uint4 xz0 = *((const uint4*)(z8 + (size_t)t0 * FD) + l8);
    float su0 = uscale[s0], sz0 = zscale[t0];

    while (e < E) {
        const uint4 xu1 = *((const uint4*)(u8 + (size_t)s1 * FD) + l8);
        const uint4 xz1 = *((const uint4*)(z8 + (size_t)t1 * FD) + l8);
        const float su1 = uscale[s1], sz1 = zscale[t1];

        const long e2  = e + 2 * S;
        const long e2c = (e2 < E) ? e2 : Em1;
        const int s2 = src[e2c], t2 = dst[e2c];

        int sum = 0;
        sum = bdot4(xu0.x, xz0.x, sum);
        sum = bdot4(xu0.y, xz0.y, sum);
        sum = bdot4(xu0.z, xz0.z, sum);
        sum = bdot4(xu0.w, xz0.w, sum);
        sum += __shfl_xor(sum, 4, 64);
        sum += __shfl_xor(sum, 2, 64);
        sum += __shfl_xor(sum, 1, 64);
        if (l8 == 0) out[e] = (float)sum * su0 * sz0 + bv;

        e += S;
        xu0 = xu1; xz0 = xz1; su0 = su1; sz0 = sz1;
        s1 = s2; t1 = t2;
    }
}

// ---------------------------------------------------------------------------
// Fallback (workspace too small): fused per-edge bilinear, fp32.
// ---------------------------------------------------------------------------
__global__ __launch_bounds__(128)
void bilinear_fused_fallback(const float* __restrict__ z, const float* __restrict__ Wg,
                             const int* __restrict__ src, const int* __restrict__ dst,
                             const float* __restrict__ bias, float* __restrict__ out,
                             int E) {
    __shared__ float Wl[FD * FD];
    __shared__ float zs[FD];
    __shared__ float red[2];
    for (int i = threadIdx.x; i < FD * FD; i += 128) Wl[i] = Wg[i];
    __syncthreads();
    const int j = (int)threadIdx.x;
    for (int e = blockIdx.x; e < E; e += gridDim.x) {
        const int s = src[e];
        const int t = dst[e];
        zs[j] = z[(size_t)s * FD + j];
        __syncthreads();
        float acc = 0.f;
        #pragma unroll 8
        for (int d = 0; d < FD; ++d) acc += zs[d] * Wl[d * FD + j];
        float p = acc * z[(size_t)t * FD + j];
        #pragma unroll
        for (int off = 32; off >= 1; off >>= 1)
            p += __shfl_xor(p, off, 64);
        if ((j & 63) == 0) red[j >> 6] = p;
        __syncthreads();
        if (j == 0) out[e] = red[0] + red[1] + bias[0];
        __syncthreads();
    }
}

extern "C" void kernel_launch(void* const* d_in, const int* in_sizes, int n_in,
                              void* d_out, int out_size, void* d_ws, size_t ws_size,
                              hipStream_t stream) {
    const float* z    = (const float*)d_in[0];
    const int*   ei   = (const int*)d_in[1];
    const float* W    = (const float*)d_in[2];
    const float* bias = (const float*)d_in[3];
    float* out = (float*)d_out;

    const int nrows = in_sizes[0] / FD;
    const int E     = in_sizes[1] / 2;
    const int* src = ei;
    const int* dst = ei + E;

    const size_t sz8 = (size_t)nrows * FD;                 // 12.8 MB int8 rows
    const size_t szs = (size_t)nrows * sizeof(float);      // 0.4 MB scales
    const size_t need = 2 * sz8 + 2 * szs + 256;

    if (ws_size >= need) {
        char* wsp = (char*)d_ws;
        unsigned char* u8  = (unsigned char*)wsp;
        unsigned char* z8  = (unsigned char*)(wsp + sz8);
        float* uscale = (float*)(wsp + 2 * sz8);
        float* zscale = (float*)(wsp + 2 * sz8 + szs);
        unsigned short* Wt = (unsigned short*)d_out;   // 32 KB staging; edge8p2
                                                       // overwrites all of d_out

        wt_kernel<<<8, 256, 0, stream>>>(W, Wt);
        const int ntiles = (nrows + 63) / 64;
        const int nb1 = (ntiles < 768) ? ntiles : 768;
        u_mfma9<<<nb1, 256, 0, stream>>>(z, Wt, u8, uscale, z8, zscale, nrows, ntiles);
        edge8p2<<<2048, 256, 0, stream>>>(u8, z8, uscale, zscale, src, dst, bias, out, E);
    } else {
        bilinear_fused_fallback<<<2048, 128, 0, stream>>>(z, W, src, dst, bias, out, E);
    }
}

// Round 15
// 56.279 us; speedup vs baseline: 1.0049x; 1.0049x over previous
//
#include <hip/hip_runtime.h>

#define FD 128  // feature dim

typedef __attribute__((ext_vector_type(8))) short short8;   // 8 bf16
typedef __attribute__((ext_vector_type(4))) float f32x4;    // MFMA acc

__device__ __forceinline__ unsigned short f2bf(float f) {
    unsigned u = __float_as_uint(f);
    u += 0x7fff + ((u >> 16) & 1);   // round-to-nearest-even
    return (unsigned short)(u >> 16);
}
__device__ __forceinline__ float bf2f(unsigned short h) {
    return __uint_as_float(((unsigned)h) << 16);
}
// exact signed-int8 dot of 4 packed bytes
__device__ __forceinline__ int bdot4(unsigned x, unsigned y, int acc) {
#if __has_builtin(__builtin_amdgcn_sdot4)
    return __builtin_amdgcn_sdot4(x, y, acc, false);
#else
    acc += (((int)(x << 24)) >> 24) * (((int)(y << 24)) >> 24);
    acc += (((int)(x << 16)) >> 24) * (((int)(y << 16)) >> 24);
    acc += (((int)(x <<  8)) >> 24) * (((int)(y <<  8)) >> 24);
    acc += (((int)x) >> 24)         * (((int)y) >> 24);
    return acc;
#endif
}
__device__ __forceinline__ unsigned pack4f(float a, float b, float c, float d, float inv) {
    const int q0 = (int)rintf(a * inv), q1 = (int)rintf(b * inv);
    const int q2 = (int)rintf(c * inv), q3 = (int)rintf(d * inv);
    return (unsigned)(q0 & 255) | ((unsigned)(q1 & 255) << 8) |
           ((unsigned)(q2 & 255) << 16) | ((unsigned)(q3 & 255) << 24);
}

// ---------------------------------------------------------------------------
// Kernel 0: Wt[n][k] = bf16(W[k][n])  (128x128), short8 outputs.
// ---------------------------------------------------------------------------
__global__ void wt_kernel(const float* __restrict__ W, unsigned short* __restrict__ Wt) {
    const int tid = blockIdx.x * 256 + (int)threadIdx.x;   // 0..2047
    const int n  = tid & 127;
    const int k0 = (tid >> 7) * 8;
    short8 w;
    #pragma unroll
    for (int j = 0; j < 8; ++j) w[j] = (short)f2bf(W[(k0 + j) * FD + n]);
    *(short8*)(Wt + (size_t)n * FD + k0) = w;
}

// ---------------------------------------------------------------------------
// Kernel 1 (v8, round-12 best): fused u8 = int8rowquant(z @ W) AND
// z8 = int8rowquant(z), swapped MFMA operands (D = Wtfrag * zfrag =>
// D[i][j] = u[j][i]; lane holds one u-row). Pure-register epilogue.
// Round 12 measured 55.5 us total — best of the 3-round plateau; the
// persistent/prefetch variants (r13/r14) were neutral, confirming a
// mixed-stream memory ceiling (~78 MB r+w) for this phase.
// ---------------------------------------------------------------------------
__global__ __launch_bounds__(256)
void u_mfma8(const float* __restrict__ z, const unsigned short* __restrict__ Wt,
             unsigned char* __restrict__ u8, float* __restrict__ uscale,
             unsigned char* __restrict__ z8, float* __restrict__ zscale,
             int nrows) {
    __shared__ unsigned short Wl[FD * FD];  // 32 KB
    char* ldsb = (char*)Wl;
    const int tid  = (int)threadIdx.x;
    const int lane = tid & 63;
    const int wave = tid >> 6;
    const int l16  = lane & 15;
    const int kq   = lane >> 4;

    const long rowbase = (long)blockIdx.x * 64 + wave * 16;
    const long r  = rowbase + l16;
    const long rc = (r < nrows) ? r : (long)(nrows - 1);
    const bool rok = (r < nrows);

    // issue z loads FIRST (latency hides under Wt staging + barrier)
    float4 zf[4][2];
    #pragma unroll
    for (int ks = 0; ks < 4; ++ks) {
        const float4* zp = (const float4*)(z + rc * FD + kq * 32 + ks * 8);
        zf[ks][0] = zp[0];
        zf[ks][1] = zp[1];
    }

    // stage Wt -> LDS, swizzled: byte = n*256 + (o ^ ((n&7)<<4))
    #pragma unroll
    for (int i = 0; i < 8; ++i) {
        const int c = i * 256 + tid;
        const int n = c >> 4;
        const int o = (c & 15) * 16;
        short8 v = *(const short8*)(Wt + (size_t)n * FD + (c & 15) * 8);
        *(short8*)(ldsb + n * 256 + (o ^ ((n & 7) << 4))) = v;
    }
    __syncthreads();

    f32x4 acc[8];
    #pragma unroll
    for (int nt = 0; nt < 8; ++nt)
        acc[nt] = (f32x4){0.f, 0.f, 0.f, 0.f};

    short8 avk[4];           // retained bf16 z-fragments (lane's 32 columns)
    float zmax = 1e-30f;

    #pragma unroll
    for (int ks = 0; ks < 4; ++ks) {
        const float4 f0 = zf[ks][0];
        const float4 f1 = zf[ks][1];
        short8 av;
        av[0] = (short)f2bf(f0.x); av[1] = (short)f2bf(f0.y);
        av[2] = (short)f2bf(f0.z); av[3] = (short)f2bf(f0.w);
        av[4] = (short)f2bf(f1.x); av[5] = (short)f2bf(f1.y);
        av[6] = (short)f2bf(f1.z); av[7] = (short)f2bf(f1.w);
        avk[ks] = av;
        #pragma unroll
        for (int j = 0; j < 8; ++j)
            zmax = fmaxf(zmax, fabsf(bf2f((unsigned short)av[j])));

        #pragma unroll
        for (int nt = 0; nt < 8; ++nt) {
            const int row = nt * 16 + l16;   // Wt row (A-fragment: A[i][k], i=l16)
            const short8 a = *(const short8*)(
                ldsb + row * 256 + ((kq * 64 + ks * 16) ^ ((row & 7) << 4)));
            // D = A(Wt) * B(z): D[i][j] = sum_k W[k][i] z[j][k] = u[j][i]
            acc[nt] = __builtin_amdgcn_mfma_f32_16x16x32_bf16(a, av, acc[nt], 0, 0, 0);
        }
    }

    // z row-max across the 4 kq lanes of this row, then pack + store z8
    zmax = fmaxf(zmax, __shfl_xor(zmax, 16, 64));
    zmax = fmaxf(zmax, __shfl_xor(zmax, 32, 64));
    {
        const float inv = 127.0f / zmax;
        uint4 p0, p1;
        p0.x = pack4f(bf2f((unsigned short)avk[0][0]), bf2f((unsigned short)avk[0][1]),
                      bf2f((unsigned short)avk[0][2]), bf2f((unsigned short)avk[0][3]), inv);
        p0.y = pack4f(bf2f((unsigned short)avk[0][4]), bf2f((unsigned short)avk[0][5]),
                      bf2f((unsigned short)avk[0][6]), bf2f((unsigned short)avk[0][7]), inv);
        p0.z = pack4f(bf2f((unsigned short)avk[1][0]), bf2f((unsigned short)avk[1][1]),
                      bf2f((unsigned short)avk[1][2]), bf2f((unsigned short)avk[1][3]), inv);
        p0.w = pack4f(bf2f((unsigned short)avk[1][4]), bf2f((unsigned short)avk[1][5]),
                      bf2f((unsigned short)avk[1][6]), bf2f((unsigned short)avk[1][7]), inv);
        p1.x = pack4f(bf2f((unsigned short)avk[2][0]), bf2f((unsigned short)avk[2][1]),
                      bf2f((unsigned short)avk[2][2]), bf2f((unsigned short)avk[2][3]), inv);
        p1.y = pack4f(bf2f((unsigned short)avk[2][4]), bf2f((unsigned short)avk[2][5]),
                      bf2f((unsigned short)avk[2][6]), bf2f((unsigned short)avk[2][7]), inv);
        p1.z = pack4f(bf2f((unsigned short)avk[3][0]), bf2f((unsigned short)avk[3][1]),
                      bf2f((unsigned short)avk[3][2]), bf2f((unsigned short)avk[3][3]), inv);
        p1.w = pack4f(bf2f((unsigned short)avk[3][4]), bf2f((unsigned short)avk[3][5]),
                      bf2f((unsigned short)avk[3][6]), bf2f((unsigned short)avk[3][7]), inv);
        if (rok) {
            *(uint4*)(z8 + r * FD + kq * 32)      = p0;
            *(uint4*)(z8 + r * FD + kq * 32 + 16) = p1;
            if (kq == 0) zscale[r] = zmax * (1.0f / 127.0f);
        }
    }

    // u epilogue, pure-register: rowmax over the lane's 32 values + 2 shuffles.
    float umax = 1e-30f;
    #pragma unroll
    for (int nt = 0; nt < 8; ++nt) {
        const f32x4 v = acc[nt];
        umax = fmaxf(umax, fmaxf(fmaxf(fabsf(v[0]), fabsf(v[1])),
                                 fmaxf(fabsf(v[2]), fabsf(v[3]))));
    }
    umax = fmaxf(umax, __shfl_xor(umax, 16, 64));
    umax = fmaxf(umax, __shfl_xor(umax, 32, 64));
    umax = fmaxf(umax, 1e-30f);
    const float uinv = 127.0f / umax;
    if (rok) {
        #pragma unroll
        for (int nt = 0; nt < 8; ++nt) {
            const f32x4 v = acc[nt];
            *(unsigned*)(u8 + r * FD + nt * 16 + kq * 4) =
                pack4f(v[0], v[1], v[2], v[3], uinv);
        }
        if (kq == 0) uscale[r] = umax * (1.0f / 127.0f);
    }
}

// ---------------------------------------------------------------------------
// Kernel 2 (v2): 3-stage pipelined int8 edge kernel (unchanged; ~26.5 us ≈
// 6.5 TB/s effective on ~173 MB of gathers — at the measured achievable
// memory ceiling; this round's 262-MB harness fills ran at 6.7 TB/s).
// ---------------------------------------------------------------------------
__global__ __launch_bounds__(256)
void edge8p2(const unsigned char* __restrict__ u8, const unsigned char* __restrict__ z8,
             const float* __restrict__ uscale, const float* __restrict__ zscale,
             const int* __restrict__ src, const int* __restrict__ dst,
             const float* __restrict__ bias, float* __restrict__ out, int E) {
    const int tid  = (int)threadIdx.x;
    const int lane = tid & 63;
    const int sub  = lane >> 3;    // edge slot within wave (0..7)
    const int l8   = lane & 7;     // 16-B slice within the 128-B row
    const long wv  = (long)blockIdx.x * 4 + (tid >> 6);
    const long S   = (long)gridDim.x * 4 * 8;
    const float bv = bias[0];
    const long Em1 = (long)E - 1;

    long e = wv * 8 + sub;
    long ec  = (e     < E) ? e     : Em1;
    long ecn = (e + S < E) ? e + S : Em1;
    int s0 = src[ec],  t0 = dst[ec];
    int s1 = src[ecn], t1 = dst[ecn];
    uint4 xu0 = *((const uint4*)(u8 + (size_t)s0 * FD) + l8);
    uint4 xz0 = *((const uint4*)(z8 + (size_t)t0 * FD) + l8);
    float su0 = uscale[s0], sz0 = zscale[t0];

    while (e < E) {
        const uint4 xu1 = *((const uint4*)(u8 + (size_t)s1 * FD) + l8);
        const uint4 xz1 = *((const uint4*)(z8 + (size_t)t1 * FD) + l8);
        const float su1 = uscale[s1], sz1 = zscale[t1];

        const long e2  = e + 2 * S;
        const long e2c = (e2 < E) ? e2 : Em1;
        const int s2 = src[e2c], t2 = dst[e2c];

        int sum = 0;
        sum = bdot4(xu0.x, xz0.x, sum);
        sum = bdot4(xu0.y, xz0.y, sum);
        sum = bdot4(xu0.z, xz0.z, sum);
        sum = bdot4(xu0.w, xz0.w, sum);
        sum += __shfl_xor(sum, 4, 64);
        sum += __shfl_xor(sum, 2, 64);
        sum += __shfl_xor(sum, 1, 64);
        if (l8 == 0) out[e] = (float)sum * su0 * sz0 + bv;

        e += S;
        xu0 = xu1; xz0 = xz1; su0 = su1; sz0 = sz1;
        s1 = s2; t1 = t2;
    }
}

// ---------------------------------------------------------------------------
// Fallback (workspace too small): fused per-edge bilinear, fp32.
// ---------------------------------------------------------------------------
__global__ __launch_bounds__(128)
void bilinear_fused_fallback(const float* __restrict__ z, const float* __restrict__ Wg,
                             const int* __restrict__ src, const int* __restrict__ dst,
                             const float* __restrict__ bias, float* __restrict__ out,
                             int E) {
    __shared__ float Wl[FD * FD];
    __shared__ float zs[FD];
    __shared__ float red[2];
    for (int i = threadIdx.x; i < FD * FD; i += 128) Wl[i] = Wg[i];
    __syncthreads();
    const int j = (int)threadIdx.x;
    for (int e = blockIdx.x; e < E; e += gridDim.x) {
        const int s = src[e];
        const int t = dst[e];
        zs[j] = z[(size_t)s * FD + j];
        __syncthreads();
        float acc = 0.f;
        #pragma unroll 8
        for (int d = 0; d < FD; ++d) acc += zs[d] * Wl[d * FD + j];
        float p = acc * z[(size_t)t * FD + j];
        #pragma unroll
        for (int off = 32; off >= 1; off >>= 1)
            p += __shfl_xor(p, off, 64);
        if ((j & 63) == 0) red[j >> 6] = p;
        __syncthreads();
        if (j == 0) out[e] = red[0] + red[1] + bias[0];
        __syncthreads();
    }
}

extern "C" void kernel_launch(void* const* d_in, const int* in_sizes, int n_in,
                              void* d_out, int out_size, void* d_ws, size_t ws_size,
                              hipStream_t stream) {
    const float* z    = (const float*)d_in[0];
    const int*   ei   = (const int*)d_in[1];
    const float* W    = (const float*)d_in[2];
    const float* bias = (const float*)d_in[3];
    float* out = (float*)d_out;

    const int nrows = in_sizes[0] / FD;
    const int E     = in_sizes[1] / 2;
    const int* src = ei;
    const int* dst = ei + E;

    const size_t sz8 = (size_t)nrows * FD;                 // 12.8 MB int8 rows
    const size_t szs = (size_t)nrows * sizeof(float);      // 0.4 MB scales
    const size_t need = 2 * sz8 + 2 * szs + 256;

    if (ws_size >= need) {
        char* wsp = (char*)d_ws;
        unsigned char* u8  = (unsigned char*)wsp;
        unsigned char* z8  = (unsigned char*)(wsp + sz8);
        float* uscale = (float*)(wsp + 2 * sz8);
        float* zscale = (float*)(wsp + 2 * sz8 + szs);
        unsigned short* Wt = (unsigned short*)d_out;   // 32 KB staging; edge8p2
                                                       // overwrites all of d_out

        wt_kernel<<<8, 256, 0, stream>>>(W, Wt);
        const int nb1 = (nrows + 63) / 64;
        u_mfma8<<<nb1, 256, 0, stream>>>(z, Wt, u8, uscale, z8, zscale, nrows);
        edge8p2<<<2048, 256, 0, stream>>>(u8, z8, uscale, zscale, src, dst, bias, out, E);
    } else {
        bilinear_fused_fallback<<<2048, 128, 0, stream>>>(z, W, src, dst, bias, out, E);
    }
}